// Round 9
// baseline (426.900 us; speedup 1.0000x reference)
//
#include <hip/hip_runtime.h>
#include <hip/hip_bf16.h>

typedef __attribute__((ext_vector_type(8))) short bf16x8;
typedef __attribute__((ext_vector_type(4))) float f32x4;

__device__ inline unsigned short f2bf(float f) {
    union { float f; unsigned u; } v; v.f = f;
    unsigned r = v.u + 0x7fff + ((v.u >> 16) & 1);
    return (unsigned short)(r >> 16);
}
__device__ inline float bf2f(unsigned short b) {
    union { unsigned u; float f; } v; v.u = ((unsigned)b) << 16;
    return v.f;
}
__device__ inline float bfu_lo(unsigned r) {
    union { unsigned u; float f; } v; v.u = r << 16;
    return v.f;
}
__device__ inline float bfu_hi(unsigned r) {
    union { unsigned u; float f; } v; v.u = r & 0xffff0000u;
    return v.f;
}

// first node v in [0,n] with start(v) >= target
__device__ inline int lbound(const int* __restrict__ local, const int* __restrict__ boff,
                             int n, int target) {
    int lo = 0, hi = n;
    while (lo < hi) {
        int m = (lo + hi) >> 1;
        int sv = local[m] + boff[m >> 10];
        if (sv < target) lo = m + 1; else hi = m;
    }
    return lo;
}

// ---------------- fused prep: cast x->bf16, split W1/W2 (transposed hi/lo), zero deg/cnt/gsum ----------------
__global__ __launch_bounds__(256) void prep_kernel(
    const float* __restrict__ x, unsigned short* __restrict__ xb,
    const float* __restrict__ W1, unsigned short* __restrict__ W1t_hi, unsigned short* __restrict__ W1t_lo,
    const float* __restrict__ W2, unsigned short* __restrict__ W2t_hi, unsigned short* __restrict__ W2t_lo,
    int* __restrict__ zero_ints, float* __restrict__ gsum, int n) {
    int tid = blockIdx.x * blockDim.x + threadIdx.x;
    int C = n * 32;                       // cast threads (4 f32 each)
    if (tid < C) {
        int base = tid * 4;
        float4 v = *(const float4*)&x[base];
        unsigned lo = (unsigned)f2bf(v.x) | ((unsigned)f2bf(v.y) << 16);
        unsigned hi = (unsigned)f2bf(v.z) | ((unsigned)f2bf(v.w) << 16);
        uint2 p; p.x = lo; p.y = hi;
        *(uint2*)&xb[base] = p;
        return;
    }
    tid -= C;
    if (tid < 65536) {
        if (tid < 32768) {                 // W1 [128][256]
            int k = tid >> 8, j = tid & 255;
            float v = W1[tid];
            unsigned short h = f2bf(v);
            W1t_hi[(size_t)j * 128 + k] = h;
            W1t_lo[(size_t)j * 128 + k] = f2bf(v - bf2f(h));
        } else {                           // W2 [256][128]
            int i2 = tid - 32768;
            int k = i2 >> 7, j = i2 & 127;
            float v = W2[i2];
            unsigned short h = f2bf(v);
            W2t_hi[(size_t)j * 256 + k] = h;
            W2t_lo[(size_t)j * 256 + k] = f2bf(v - bf2f(h));
        }
        return;
    }
    tid -= 65536;
    if (tid < 2 * n) { zero_ints[tid] = 0; return; }   // deg, cnt
    tid -= 2 * n;
    if (tid < 128) gsum[tid] = 0.f;
}

// ---------------- degree histogram ----------------
__global__ void hist_kernel(const int* __restrict__ dst, int* __restrict__ deg, int nE) {
    int e = blockIdx.x * blockDim.x + threadIdx.x;
    if (e < nE) atomicAdd(&deg[dst[e]], 1);
}

// ---------------- scanA: per-1024-block exclusive scan + dinv + block sums ----------------
__global__ __launch_bounds__(1024) void scanA_kernel(const int* __restrict__ deg,
                                                     int* __restrict__ local,
                                                     float* __restrict__ dinv,
                                                     int* __restrict__ bsum, int n) {
    __shared__ int wsum[16];
    __shared__ int woff[16];
    int t = threadIdx.x, lane = t & 63, wid = t >> 6;
    int i = blockIdx.x * 1024 + t;
    int val = (i < n) ? deg[i] : 0;
    if (i < n) dinv[i] = rsqrtf((float)(val + 1));
    int inc = val;
    for (int s = 1; s < 64; s <<= 1) {
        int tmp = __shfl_up(inc, s);
        if (lane >= s) inc += tmp;
    }
    if (lane == 63) wsum[wid] = inc;
    __syncthreads();
    if (wid == 0) {
        int w = (lane < 16) ? wsum[lane] : 0;
        for (int s = 1; s < 16; s <<= 1) {
            int tmp = __shfl_up(w, s);
            if (lane >= s) w += tmp;
        }
        if (lane < 16) woff[lane] = w - wsum[lane];
        if (lane == 15) bsum[blockIdx.x] = w;
    }
    __syncthreads();
    if (i < n) local[i] = woff[wid] + (inc - val);
}

// ---------------- scanB: one wave scans block sums (nb <= 64) ----------------
__global__ void scanB_kernel(const int* __restrict__ bsum, int* __restrict__ boff, int nb) {
    int lane = threadIdx.x & 63;
    int v = (lane < nb) ? bsum[lane] : 0;
    int inc = v;
    for (int s = 1; s < 64; s <<= 1) {
        int tmp = __shfl_up(inc, s);
        if (lane >= s) inc += tmp;
    }
    if (lane < nb) boff[lane] = inc - v;
}

// ---------------- CSR fill ----------------
__global__ void fill_kernel(const int* __restrict__ src, const int* __restrict__ dst,
                            const int* __restrict__ local, const int* __restrict__ boff,
                            int* __restrict__ cnt, const float* __restrict__ dinv,
                            int2* __restrict__ csr, int nE) {
    int e = blockIdx.x * blockDim.x + threadIdx.x;
    if (e >= nE) return;
    int s = src[e], d = dst[e];
    int pos = local[d] + boff[d >> 10] + atomicAdd(&cnt[d], 1);
    float w = dinv[s] * dinv[d];
    csr[pos] = make_int2(s, __float_as_int(w));
}

// ---------------- conv1 gather (bf16 rows, 8-way MLP, edge-balanced ranges) ----------------
__global__ __launch_bounds__(256) void gather1_kernel(const unsigned int* __restrict__ xb,
                                                      const int2* __restrict__ csr,
                                                      const int* __restrict__ local,
                                                      const int* __restrict__ boff,
                                                      const int* __restrict__ deg,
                                                      const float* __restrict__ dinv,
                                                      unsigned int* __restrict__ xin_hi,
                                                      unsigned int* __restrict__ xin_lo,
                                                      int n, int E) {
    int wid = threadIdx.x >> 6;
    int lane = threadIdx.x & 63;
    int W = gridDim.x * 4;
    int w = blockIdx.x * 4 + wid;
    int ns = lbound(local, boff, n, (int)((long)w * E / W));
    int ne = (w == W - 1) ? n : lbound(local, boff, n, (int)((long)(w + 1) * E / W));
    for (int node = ns; node < ne; ++node) {
        int p = local[node] + boff[node >> 10];
        int e0 = p + deg[node];
        unsigned rs = xb[(size_t)node * 64 + lane];
        float a0 = 0.f, a1 = 0.f, b0 = 0.f, b1 = 0.f;
        float c0 = 0.f, c1 = 0.f, d0v = 0.f, d1v = 0.f;
        for (; p + 7 < e0; p += 8) {
            int2 q0 = csr[p], q1 = csr[p + 1], q2 = csr[p + 2], q3 = csr[p + 3];
            int2 q4 = csr[p + 4], q5 = csr[p + 5], q6 = csr[p + 6], q7 = csr[p + 7];
            unsigned r0 = xb[(size_t)q0.x * 64 + lane];
            unsigned r1 = xb[(size_t)q1.x * 64 + lane];
            unsigned r2 = xb[(size_t)q2.x * 64 + lane];
            unsigned r3 = xb[(size_t)q3.x * 64 + lane];
            unsigned r4 = xb[(size_t)q4.x * 64 + lane];
            unsigned r5 = xb[(size_t)q5.x * 64 + lane];
            unsigned r6 = xb[(size_t)q6.x * 64 + lane];
            unsigned r7 = xb[(size_t)q7.x * 64 + lane];
            float w0 = __int_as_float(q0.y), w1 = __int_as_float(q1.y);
            float w2 = __int_as_float(q2.y), w3 = __int_as_float(q3.y);
            float w4 = __int_as_float(q4.y), w5 = __int_as_float(q5.y);
            float w6 = __int_as_float(q6.y), w7 = __int_as_float(q7.y);
            a0 += w0 * bfu_lo(r0); a1 += w0 * bfu_hi(r0);
            b0 += w1 * bfu_lo(r1); b1 += w1 * bfu_hi(r1);
            c0 += w2 * bfu_lo(r2); c1 += w2 * bfu_hi(r2);
            d0v += w3 * bfu_lo(r3); d1v += w3 * bfu_hi(r3);
            a0 += w4 * bfu_lo(r4); a1 += w4 * bfu_hi(r4);
            b0 += w5 * bfu_lo(r5); b1 += w5 * bfu_hi(r5);
            c0 += w6 * bfu_lo(r6); c1 += w6 * bfu_hi(r6);
            d0v += w7 * bfu_lo(r7); d1v += w7 * bfu_hi(r7);
        }
        for (; p + 3 < e0; p += 4) {
            int2 q0 = csr[p], q1 = csr[p + 1], q2 = csr[p + 2], q3 = csr[p + 3];
            unsigned r0 = xb[(size_t)q0.x * 64 + lane];
            unsigned r1 = xb[(size_t)q1.x * 64 + lane];
            unsigned r2 = xb[(size_t)q2.x * 64 + lane];
            unsigned r3 = xb[(size_t)q3.x * 64 + lane];
            float w0 = __int_as_float(q0.y), w1 = __int_as_float(q1.y);
            float w2 = __int_as_float(q2.y), w3 = __int_as_float(q3.y);
            a0 += w0 * bfu_lo(r0); a1 += w0 * bfu_hi(r0);
            b0 += w1 * bfu_lo(r1); b1 += w1 * bfu_hi(r1);
            c0 += w2 * bfu_lo(r2); c1 += w2 * bfu_hi(r2);
            d0v += w3 * bfu_lo(r3); d1v += w3 * bfu_hi(r3);
        }
        for (; p < e0; ++p) {
            int2 q = csr[p];
            float ww = __int_as_float(q.y);
            unsigned r = xb[(size_t)q.x * 64 + lane];
            a0 += ww * bfu_lo(r); a1 += ww * bfu_hi(r);
        }
        a0 = (a0 + b0) + (c0 + d0v);
        a1 = (a1 + b1) + (c1 + d1v);
        float di = dinv[node];
        float d2 = di * di;
        a0 += d2 * bfu_lo(rs);
        a1 += d2 * bfu_hi(rs);
        unsigned short h0 = f2bf(a0), h1 = f2bf(a1);
        xin_hi[(size_t)node * 64 + lane] = (unsigned)h0 | ((unsigned)h1 << 16);
        unsigned short l0 = f2bf(a0 - bf2f(h0)), l1 = f2bf(a1 - bf2f(h1));
        xin_lo[(size_t)node * 64 + lane] = (unsigned)l0 | ((unsigned)l1 << 16);
    }
}

// ---------------- split-bf16 MFMA GEMM, 32 rows/wave, 2 j-tiles (128 cols) per pass ----------------
// A hi(/lo) bf16 row-major [n,K]; W transposed hi/lo bf16 [NOUT][K].
// Grid: (ceil(n/128), NOUT/128). Block: 4 waves; wave = 32 rows x 128 cols.
template <int K, int NOUT, bool BIAS_RELU, bool A_SPLIT>
__global__ __launch_bounds__(256) void mfma_gemm_kernel(
    const unsigned short* __restrict__ Ahi, const unsigned short* __restrict__ Alo,
    const unsigned short* __restrict__ Wthi, const unsigned short* __restrict__ Wtlo,
    const float* __restrict__ bias,
    unsigned short* __restrict__ O, int n) {
    int w = threadIdx.x >> 6, l = threadIdx.x & 63;
    int m0 = blockIdx.x * 128 + w * 32;
    int j0 = blockIdx.y * 128;
    int col16 = l & 15;
    int koff = (l >> 4) * 8;
    int rowA0 = m0 + col16;       if (rowA0 >= n) rowA0 = n - 1;
    int rowA1 = m0 + 16 + col16;  if (rowA1 >= n) rowA1 = n - 1;
    f32x4 acc[2][2][4];
#pragma unroll
    for (int g = 0; g < 2; ++g)
#pragma unroll
        for (int jt = 0; jt < 2; ++jt)
#pragma unroll
            for (int c = 0; c < 4; ++c) acc[g][jt][c] = (f32x4){0.f, 0.f, 0.f, 0.f};
    for (int k0 = 0; k0 < K; k0 += 32) {
        bf16x8 ah0 = *(const bf16x8*)&Ahi[(size_t)rowA0 * K + k0 + koff];
        bf16x8 ah1 = *(const bf16x8*)&Ahi[(size_t)rowA1 * K + k0 + koff];
        bf16x8 al0, al1;
        if (A_SPLIT) {
            al0 = *(const bf16x8*)&Alo[(size_t)rowA0 * K + k0 + koff];
            al1 = *(const bf16x8*)&Alo[(size_t)rowA1 * K + k0 + koff];
        }
#pragma unroll
        for (int jt = 0; jt < 2; ++jt) {
#pragma unroll
            for (int c = 0; c < 4; ++c) {
                size_t wb = (size_t)(j0 + jt * 64 + c * 16 + col16) * K + k0 + koff;
                bf16x8 wh = *(const bf16x8*)&Wthi[wb];
                bf16x8 wl = *(const bf16x8*)&Wtlo[wb];
                acc[0][jt][c] = __builtin_amdgcn_mfma_f32_16x16x32_bf16(ah0, wh, acc[0][jt][c], 0, 0, 0);
                if (A_SPLIT) acc[0][jt][c] = __builtin_amdgcn_mfma_f32_16x16x32_bf16(al0, wh, acc[0][jt][c], 0, 0, 0);
                acc[0][jt][c] = __builtin_amdgcn_mfma_f32_16x16x32_bf16(ah0, wl, acc[0][jt][c], 0, 0, 0);
                acc[1][jt][c] = __builtin_amdgcn_mfma_f32_16x16x32_bf16(ah1, wh, acc[1][jt][c], 0, 0, 0);
                if (A_SPLIT) acc[1][jt][c] = __builtin_amdgcn_mfma_f32_16x16x32_bf16(al1, wh, acc[1][jt][c], 0, 0, 0);
                acc[1][jt][c] = __builtin_amdgcn_mfma_f32_16x16x32_bf16(ah1, wl, acc[1][jt][c], 0, 0, 0);
            }
        }
    }
#pragma unroll
    for (int g = 0; g < 2; ++g) {
#pragma unroll
        for (int jt = 0; jt < 2; ++jt) {
#pragma unroll
            for (int c = 0; c < 4; ++c) {
                int col = j0 + jt * 64 + c * 16 + col16;
#pragma unroll
                for (int r = 0; r < 4; ++r) {
                    int orow = m0 + g * 16 + (l >> 4) * 4 + r;
                    if (orow >= n) continue;
                    float v = acc[g][jt][c][r];
                    if (BIAS_RELU) v = fmaxf(v + bias[col], 0.f);
                    O[(size_t)orow * NOUT + col] = f2bf(v);
                }
            }
        }
    }
}

// ---------------- conv2 gather (bf16, 8-way MLP, edge-balanced) + epilogue + logits + edge partials + gsum ----------------
__global__ __launch_bounds__(256) void conv2_fused_kernel(
    const unsigned int* __restrict__ h2b, const int2* __restrict__ csr,
    const int* __restrict__ local, const int* __restrict__ boff,
    const int* __restrict__ deg,
    const float* __restrict__ dinv, const float* __restrict__ b2,
    const float* __restrict__ npW, const float* __restrict__ npb,
    const float* __restrict__ epW, const float* __restrict__ epb,
    float* __restrict__ out_nl, float* __restrict__ uv,
    float* __restrict__ gsum, int n, int E) {
    __shared__ float lgs[4][128];
    int lane = threadIdx.x & 63;
    int wid = threadIdx.x >> 6;
    int d0 = lane * 2, d1 = lane * 2 + 1;
    float wn00 = npW[d0 * 3 + 0], wn10 = npW[d0 * 3 + 1], wn20 = npW[d0 * 3 + 2];
    float wn01 = npW[d1 * 3 + 0], wn11 = npW[d1 * 3 + 1], wn21 = npW[d1 * 3 + 2];
    float wu00 = epW[d0 * 2 + 0], wu10 = epW[d0 * 2 + 1];
    float wu01 = epW[d1 * 2 + 0], wu11 = epW[d1 * 2 + 1];
    float wv00 = epW[(d0 + 128) * 2 + 0], wv10 = epW[(d0 + 128) * 2 + 1];
    float wv01 = epW[(d1 + 128) * 2 + 0], wv11 = epW[(d1 + 128) * 2 + 1];
    float b20 = b2[d0], b21 = b2[d1];
    float npb0 = npb[0], npb1 = npb[1], npb2 = npb[2];
    float epb0 = epb[0], epb1 = epb[1];
    float p0 = 0.f, p1 = 0.f;   // pool partials

    int W = gridDim.x * 4;
    int w = blockIdx.x * 4 + wid;
    int ns = lbound(local, boff, n, (int)((long)w * E / W));
    int ne = (w == W - 1) ? n : lbound(local, boff, n, (int)((long)(w + 1) * E / W));
    for (int node = ns; node < ne; ++node) {
        int p = local[node] + boff[node >> 10];
        int e0 = p + deg[node];
        unsigned rs = h2b[(size_t)node * 64 + lane];
        float a0 = 0.f, a1 = 0.f, b0 = 0.f, b1 = 0.f;
        float c0 = 0.f, c1 = 0.f, e0v = 0.f, e1v = 0.f;
        for (; p + 7 < e0; p += 8) {
            int2 q0 = csr[p], q1 = csr[p + 1], q2 = csr[p + 2], q3 = csr[p + 3];
            int2 q4 = csr[p + 4], q5 = csr[p + 5], q6 = csr[p + 6], q7 = csr[p + 7];
            unsigned r0 = h2b[(size_t)q0.x * 64 + lane];
            unsigned r1 = h2b[(size_t)q1.x * 64 + lane];
            unsigned r2 = h2b[(size_t)q2.x * 64 + lane];
            unsigned r3 = h2b[(size_t)q3.x * 64 + lane];
            unsigned r4 = h2b[(size_t)q4.x * 64 + lane];
            unsigned r5 = h2b[(size_t)q5.x * 64 + lane];
            unsigned r6 = h2b[(size_t)q6.x * 64 + lane];
            unsigned r7 = h2b[(size_t)q7.x * 64 + lane];
            float w0 = __int_as_float(q0.y), w1 = __int_as_float(q1.y);
            float w2 = __int_as_float(q2.y), w3 = __int_as_float(q3.y);
            float w4 = __int_as_float(q4.y), w5 = __int_as_float(q5.y);
            float w6 = __int_as_float(q6.y), w7 = __int_as_float(q7.y);
            a0 += w0 * bfu_lo(r0); a1 += w0 * bfu_hi(r0);
            b0 += w1 * bfu_lo(r1); b1 += w1 * bfu_hi(r1);
            c0 += w2 * bfu_lo(r2); c1 += w2 * bfu_hi(r2);
            e0v += w3 * bfu_lo(r3); e1v += w3 * bfu_hi(r3);
            a0 += w4 * bfu_lo(r4); a1 += w4 * bfu_hi(r4);
            b0 += w5 * bfu_lo(r5); b1 += w5 * bfu_hi(r5);
            c0 += w6 * bfu_lo(r6); c1 += w6 * bfu_hi(r6);
            e0v += w7 * bfu_lo(r7); e1v += w7 * bfu_hi(r7);
        }
        for (; p + 3 < e0; p += 4) {
            int2 q0 = csr[p], q1 = csr[p + 1], q2 = csr[p + 2], q3 = csr[p + 3];
            unsigned r0 = h2b[(size_t)q0.x * 64 + lane];
            unsigned r1 = h2b[(size_t)q1.x * 64 + lane];
            unsigned r2 = h2b[(size_t)q2.x * 64 + lane];
            unsigned r3 = h2b[(size_t)q3.x * 64 + lane];
            float w0 = __int_as_float(q0.y), w1 = __int_as_float(q1.y);
            float w2 = __int_as_float(q2.y), w3 = __int_as_float(q3.y);
            a0 += w0 * bfu_lo(r0); a1 += w0 * bfu_hi(r0);
            b0 += w1 * bfu_lo(r1); b1 += w1 * bfu_hi(r1);
            c0 += w2 * bfu_lo(r2); c1 += w2 * bfu_hi(r2);
            e0v += w3 * bfu_lo(r3); e1v += w3 * bfu_hi(r3);
        }
        for (; p < e0; ++p) {
            int2 q = csr[p];
            float ww = __int_as_float(q.y);
            unsigned r = h2b[(size_t)q.x * 64 + lane];
            a0 += ww * bfu_lo(r); a1 += ww * bfu_hi(r);
        }
        a0 = (a0 + b0) + (c0 + e0v);
        a1 = (a1 + b1) + (c1 + e1v);
        float di = dinv[node];
        float d2 = di * di;
        a0 = fmaxf(a0 + d2 * bfu_lo(rs) + b20, 0.f);
        a1 = fmaxf(a1 + d2 * bfu_hi(rs) + b21, 0.f);
        p0 += a0;
        p1 += a1;
        float n0 = a0 * wn00 + a1 * wn01;
        float n1 = a0 * wn10 + a1 * wn11;
        float n2 = a0 * wn20 + a1 * wn21;
        float u0 = a0 * wu00 + a1 * wu01;
        float u1 = a0 * wu10 + a1 * wu11;
        float v0 = a0 * wv00 + a1 * wv01;
        float v1 = a0 * wv10 + a1 * wv11;
        for (int off = 32; off; off >>= 1) {
            n0 += __shfl_xor(n0, off);
            n1 += __shfl_xor(n1, off);
            n2 += __shfl_xor(n2, off);
            u0 += __shfl_xor(u0, off);
            u1 += __shfl_xor(u1, off);
            v0 += __shfl_xor(v0, off);
            v1 += __shfl_xor(v1, off);
        }
        if (lane == 0) {
            out_nl[(size_t)node * 3 + 0] = n0 + npb0;
            out_nl[(size_t)node * 3 + 1] = n1 + npb1;
            out_nl[(size_t)node * 3 + 2] = n2 + npb2;
            float4 o;
            o.x = u0 + epb0; o.y = u1 + epb1; o.z = v0; o.w = v1;
            *(float4*)&uv[(size_t)node * 4] = o;
        }
    }
    lgs[wid][d0] = p0;
    lgs[wid][d1] = p1;
    __syncthreads();
    int t = threadIdx.x;
    if (t < 128) {
        float tot = lgs[0][t] + lgs[1][t] + lgs[2][t] + lgs[3][t];
        atomicAdd(&gsum[t], tot);
    }
}

// ---------------- edge logits (blocks 1..) + pooled heads (block 0) ----------------
__global__ __launch_bounds__(256) void edge_head_kernel(
    const float* __restrict__ uv, const int* __restrict__ src, const int* __restrict__ dst,
    float* __restrict__ out_el, int nE,
    const float* __restrict__ gsum,
    const float* __restrict__ fc1W, const float* __restrict__ fc1b,
    const float* __restrict__ fc2W, const float* __restrict__ fc2b,
    const float* __restrict__ gpW, const float* __restrict__ gpb,
    float* __restrict__ out_gl, float* __restrict__ out_val, int n) {
    if (blockIdx.x == 0) {
        __shared__ float g[128];
        __shared__ float red[256];
        int t = threadIdx.x;
        if (t < 128) g[t] = gsum[t] * (1.0f / (float)n);
        __syncthreads();
        float v = fc1b[t];
#pragma unroll
        for (int k = 0; k < 128; ++k) v += g[k] * fc1W[k * 256 + t];
        v = fmaxf(v, 0.0f);
        red[t] = v * fc2W[t];
        __syncthreads();
        for (int s = 128; s > 0; s >>= 1) { if (t < s) red[t] += red[t + s]; __syncthreads(); }
        if (t == 0) out_val[0] = red[0] + fc2b[0];
        __syncthreads();
        red[t] = (t < 128) ? g[t] * gpW[t] : 0.0f;
        __syncthreads();
        for (int s = 128; s > 0; s >>= 1) { if (t < s) red[t] += red[t + s]; __syncthreads(); }
        if (t == 0) out_gl[0] = red[0] + gpb[0];
        return;
    }
    int e = (blockIdx.x - 1) * blockDim.x + threadIdx.x;
    if (e >= nE) return;
    int s = src[e], d = dst[e];
    float2 u = *(const float2*)&uv[(size_t)s * 4];
    float2 v = *(const float2*)&uv[(size_t)d * 4 + 2];
    float2 o; o.x = u.x + v.x; o.y = u.y + v.y;
    *(float2*)&out_el[(size_t)e * 2] = o;
}

extern "C" void kernel_launch(void* const* d_in, const int* in_sizes, int n_in,
                              void* d_out, int out_size, void* d_ws, size_t ws_size,
                              hipStream_t stream) {
    const float* x    = (const float*)d_in[0];
    const int*   ei   = (const int*)d_in[1];
    const float* W1   = (const float*)d_in[2];
    const float* b1   = (const float*)d_in[3];
    const float* W2   = (const float*)d_in[4];
    const float* b2   = (const float*)d_in[5];
    const float* fc1W = (const float*)d_in[6];
    const float* fc1b = (const float*)d_in[7];
    const float* fc2W = (const float*)d_in[8];
    const float* fc2b = (const float*)d_in[9];
    const float* npW  = (const float*)d_in[10];
    const float* npb  = (const float*)d_in[11];
    const float* epW  = (const float*)d_in[12];
    const float* epb  = (const float*)d_in[13];
    const float* gpW  = (const float*)d_in[14];
    const float* gpb  = (const float*)d_in[15];
    float* out = (float*)d_out;

    const int n = in_sizes[0] / 128;   // 50000
    const int E = in_sizes[1] / 2;     // 800000
    const int* src = ei;
    const int* dst = ei + E;
    const int nb = (n + 1023) / 1024;  // scan blocks (<= 64)

    // workspace layout (256 B aligned chunks)
    char* p = (char*)d_ws;
    auto alloc = [&](size_t bytes) { char* r = p; p += (bytes + 255) & ~(size_t)255; return r; };
    unsigned short* xb     = (unsigned short*)alloc((size_t)n * 128 * 2);  // reused as h2b
    unsigned short* xin_hi = (unsigned short*)alloc((size_t)n * 128 * 2);
    unsigned short* xin_lo = (unsigned short*)alloc((size_t)n * 128 * 2);
    unsigned short* h      = (unsigned short*)alloc((size_t)n * 256 * 2);
    unsigned short* W1t_hi = (unsigned short*)alloc(128 * 256 * 2);
    unsigned short* W1t_lo = (unsigned short*)alloc(128 * 256 * 2);
    unsigned short* W2t_hi = (unsigned short*)alloc(256 * 128 * 2);
    unsigned short* W2t_lo = (unsigned short*)alloc(256 * 128 * 2);
    int2*  csr    = (int2*)alloc((size_t)E * 8);
    int*   deg    = (int*)alloc((size_t)n * 4 * 2);   // deg, cnt (zeroed in prep)
    int*   cnt    = deg + n;
    int*   local  = (int*)alloc((size_t)n * 4);
    int*   bsum   = (int*)alloc(64 * 4);
    int*   boff   = (int*)alloc(64 * 4);
    float* dinv   = (float*)alloc((size_t)n * 4);
    float* uv     = (float*)alloc((size_t)n * 16);
    float* gsum   = (float*)alloc(512);
    unsigned short* h2b = xb;   // alias: xb dead after gather1

    // output layout
    float* out_nl  = out;
    float* out_el  = out + (size_t)n * 3;
    float* out_gl  = out + (size_t)n * 3 + (size_t)E * 2;
    float* out_val = out_gl + 1;

    // prep: cast + wsplits + zero (deg/cnt + gsum)
    {
        long total = (long)n * 32 + 65536 + 2L * n + 128;
        int blocks = (int)((total + 255) / 256);
        prep_kernel<<<blocks, 256, 0, stream>>>(x, xb, W1, W1t_hi, W1t_lo,
                                                W2, W2t_hi, W2t_lo, deg, gsum, n);
    }

    hist_kernel<<<(E + 255) / 256, 256, 0, stream>>>(dst, deg, E);
    scanA_kernel<<<nb, 1024, 0, stream>>>(deg, local, dinv, bsum, n);
    scanB_kernel<<<1, 64, 0, stream>>>(bsum, boff, nb);
    fill_kernel<<<(E + 255) / 256, 256, 0, stream>>>(src, dst, local, boff, cnt, dinv, csr, E);

    gather1_kernel<<<2048, 256, 0, stream>>>((const unsigned int*)xb, csr, local, boff,
                                             deg, dinv, (unsigned int*)xin_hi,
                                             (unsigned int*)xin_lo, n, E);

    dim3 g1((n + 127) / 128, 2);
    mfma_gemm_kernel<128, 256, true, true><<<g1, 256, 0, stream>>>(xin_hi, xin_lo, W1t_hi, W1t_lo,
                                                                   b1, h, n);
    dim3 g2((n + 127) / 128, 1);
    mfma_gemm_kernel<256, 128, false, false><<<g2, 256, 0, stream>>>(h, nullptr, W2t_hi, W2t_lo,
                                                                     nullptr, h2b, n);

    conv2_fused_kernel<<<2048, 256, 0, stream>>>((const unsigned int*)h2b, csr, local, boff,
                                                 deg, dinv, b2, npW, npb, epW, epb,
                                                 out_nl, uv, gsum, n, E);

    edge_head_kernel<<<1 + (E + 255) / 256, 256, 0, stream>>>(uv, src, dst, out_el, E,
                                                              gsum, fc1W, fc1b, fc2W, fc2b,
                                                              gpW, gpb, out_gl, out_val, n);
}

// Round 10
// 394.167 us; speedup vs baseline: 1.0830x; 1.0830x over previous
//
#include <hip/hip_runtime.h>
#include <hip/hip_bf16.h>

typedef __attribute__((ext_vector_type(8))) short bf16x8;
typedef __attribute__((ext_vector_type(4))) float f32x4;

__device__ inline unsigned short f2bf(float f) {
    union { float f; unsigned u; } v; v.f = f;
    unsigned r = v.u + 0x7fff + ((v.u >> 16) & 1);
    return (unsigned short)(r >> 16);
}
__device__ inline float bf2f(unsigned short b) {
    union { unsigned u; float f; } v; v.u = ((unsigned)b) << 16;
    return v.f;
}
__device__ inline float bfu_lo(unsigned r) {
    union { unsigned u; float f; } v; v.u = r << 16;
    return v.f;
}
__device__ inline float bfu_hi(unsigned r) {
    union { unsigned u; float f; } v; v.u = r & 0xffff0000u;
    return v.f;
}

// ---------------- fused prep: cast x->bf16, split W1/W2 (transposed hi/lo), zero deg/cnt/gsum ----------------
__global__ __launch_bounds__(256) void prep_kernel(
    const float* __restrict__ x, unsigned short* __restrict__ xb,
    const float* __restrict__ W1, unsigned short* __restrict__ W1t_hi, unsigned short* __restrict__ W1t_lo,
    const float* __restrict__ W2, unsigned short* __restrict__ W2t_hi, unsigned short* __restrict__ W2t_lo,
    int* __restrict__ zero_ints, float* __restrict__ gsum, int n) {
    int tid = blockIdx.x * blockDim.x + threadIdx.x;
    int C = n * 32;                       // cast threads (4 f32 each)
    if (tid < C) {
        int base = tid * 4;
        float4 v = *(const float4*)&x[base];
        unsigned lo = (unsigned)f2bf(v.x) | ((unsigned)f2bf(v.y) << 16);
        unsigned hi = (unsigned)f2bf(v.z) | ((unsigned)f2bf(v.w) << 16);
        uint2 p; p.x = lo; p.y = hi;
        *(uint2*)&xb[base] = p;
        return;
    }
    tid -= C;
    if (tid < 65536) {
        if (tid < 32768) {                 // W1 [128][256]
            int k = tid >> 8, j = tid & 255;
            float v = W1[tid];
            unsigned short h = f2bf(v);
            W1t_hi[(size_t)j * 128 + k] = h;
            W1t_lo[(size_t)j * 128 + k] = f2bf(v - bf2f(h));
        } else {                           // W2 [256][128]
            int i2 = tid - 32768;
            int k = i2 >> 7, j = i2 & 127;
            float v = W2[i2];
            unsigned short h = f2bf(v);
            W2t_hi[(size_t)j * 256 + k] = h;
            W2t_lo[(size_t)j * 256 + k] = f2bf(v - bf2f(h));
        }
        return;
    }
    tid -= 65536;
    if (tid < 2 * n) { zero_ints[tid] = 0; return; }   // deg, cnt
    tid -= 2 * n;
    if (tid < 128) gsum[tid] = 0.f;
}

// ---------------- degree histogram ----------------
__global__ void hist_kernel(const int* __restrict__ dst, int* __restrict__ deg, int nE) {
    int e = blockIdx.x * blockDim.x + threadIdx.x;
    if (e < nE) atomicAdd(&deg[dst[e]], 1);
}

// ---------------- scanA: per-1024-block exclusive scan + dinv + block sums ----------------
__global__ __launch_bounds__(1024) void scanA_kernel(const int* __restrict__ deg,
                                                     int* __restrict__ local,
                                                     float* __restrict__ dinv,
                                                     int* __restrict__ bsum, int n) {
    __shared__ int wsum[16];
    __shared__ int woff[16];
    int t = threadIdx.x, lane = t & 63, wid = t >> 6;
    int i = blockIdx.x * 1024 + t;
    int val = (i < n) ? deg[i] : 0;
    if (i < n) dinv[i] = rsqrtf((float)(val + 1));
    int inc = val;
    for (int s = 1; s < 64; s <<= 1) {
        int tmp = __shfl_up(inc, s);
        if (lane >= s) inc += tmp;
    }
    if (lane == 63) wsum[wid] = inc;
    __syncthreads();
    if (wid == 0) {
        int w = (lane < 16) ? wsum[lane] : 0;
        for (int s = 1; s < 16; s <<= 1) {
            int tmp = __shfl_up(w, s);
            if (lane >= s) w += tmp;
        }
        if (lane < 16) woff[lane] = w - wsum[lane];
        if (lane == 15) bsum[blockIdx.x] = w;
    }
    __syncthreads();
    if (i < n) local[i] = woff[wid] + (inc - val);
}

// ---------------- scanB: one wave scans block sums (nb <= 64) ----------------
__global__ void scanB_kernel(const int* __restrict__ bsum, int* __restrict__ boff, int nb) {
    int lane = threadIdx.x & 63;
    int v = (lane < nb) ? bsum[lane] : 0;
    int inc = v;
    for (int s = 1; s < 64; s <<= 1) {
        int tmp = __shfl_up(inc, s);
        if (lane >= s) inc += tmp;
    }
    if (lane < nb) boff[lane] = inc - v;
}

// ---------------- CSR fill ----------------
__global__ void fill_kernel(const int* __restrict__ src, const int* __restrict__ dst,
                            const int* __restrict__ local, const int* __restrict__ boff,
                            int* __restrict__ cnt, const float* __restrict__ dinv,
                            int2* __restrict__ csr, int nE) {
    int e = blockIdx.x * blockDim.x + threadIdx.x;
    if (e >= nE) return;
    int s = src[e], d = dst[e];
    int pos = local[d] + boff[d >> 10] + atomicAdd(&cnt[d], 1);
    float w = dinv[s] * dinv[d];
    csr[pos] = make_int2(s, __float_as_int(w));
}

// ---------------- conv1 gather (bf16 rows, 8-way MLP) — r6 form ----------------
__global__ __launch_bounds__(256) void gather1_kernel(const unsigned int* __restrict__ xb,
                                                      const int2* __restrict__ csr,
                                                      const int* __restrict__ local,
                                                      const int* __restrict__ boff,
                                                      const int* __restrict__ deg,
                                                      const float* __restrict__ dinv,
                                                      unsigned int* __restrict__ xin_hi,
                                                      unsigned int* __restrict__ xin_lo, int n) {
    int node = blockIdx.x * 4 + (threadIdx.x >> 6);
    int lane = threadIdx.x & 63;
    if (node >= n) return;
    int p = local[node] + boff[node >> 10];
    int e0 = p + deg[node];
    unsigned rs = xb[(size_t)node * 64 + lane];
    float a0 = 0.f, a1 = 0.f, b0 = 0.f, b1 = 0.f;
    float c0 = 0.f, c1 = 0.f, d0v = 0.f, d1v = 0.f;
    for (; p + 7 < e0; p += 8) {
        int2 q0 = csr[p], q1 = csr[p + 1], q2 = csr[p + 2], q3 = csr[p + 3];
        int2 q4 = csr[p + 4], q5 = csr[p + 5], q6 = csr[p + 6], q7 = csr[p + 7];
        unsigned r0 = xb[(size_t)q0.x * 64 + lane];
        unsigned r1 = xb[(size_t)q1.x * 64 + lane];
        unsigned r2 = xb[(size_t)q2.x * 64 + lane];
        unsigned r3 = xb[(size_t)q3.x * 64 + lane];
        unsigned r4 = xb[(size_t)q4.x * 64 + lane];
        unsigned r5 = xb[(size_t)q5.x * 64 + lane];
        unsigned r6 = xb[(size_t)q6.x * 64 + lane];
        unsigned r7 = xb[(size_t)q7.x * 64 + lane];
        float w0 = __int_as_float(q0.y), w1 = __int_as_float(q1.y);
        float w2 = __int_as_float(q2.y), w3 = __int_as_float(q3.y);
        float w4 = __int_as_float(q4.y), w5 = __int_as_float(q5.y);
        float w6 = __int_as_float(q6.y), w7 = __int_as_float(q7.y);
        a0 += w0 * bfu_lo(r0); a1 += w0 * bfu_hi(r0);
        b0 += w1 * bfu_lo(r1); b1 += w1 * bfu_hi(r1);
        c0 += w2 * bfu_lo(r2); c1 += w2 * bfu_hi(r2);
        d0v += w3 * bfu_lo(r3); d1v += w3 * bfu_hi(r3);
        a0 += w4 * bfu_lo(r4); a1 += w4 * bfu_hi(r4);
        b0 += w5 * bfu_lo(r5); b1 += w5 * bfu_hi(r5);
        c0 += w6 * bfu_lo(r6); c1 += w6 * bfu_hi(r6);
        d0v += w7 * bfu_lo(r7); d1v += w7 * bfu_hi(r7);
    }
    for (; p + 3 < e0; p += 4) {
        int2 q0 = csr[p], q1 = csr[p + 1], q2 = csr[p + 2], q3 = csr[p + 3];
        unsigned r0 = xb[(size_t)q0.x * 64 + lane];
        unsigned r1 = xb[(size_t)q1.x * 64 + lane];
        unsigned r2 = xb[(size_t)q2.x * 64 + lane];
        unsigned r3 = xb[(size_t)q3.x * 64 + lane];
        float w0 = __int_as_float(q0.y), w1 = __int_as_float(q1.y);
        float w2 = __int_as_float(q2.y), w3 = __int_as_float(q3.y);
        a0 += w0 * bfu_lo(r0); a1 += w0 * bfu_hi(r0);
        b0 += w1 * bfu_lo(r1); b1 += w1 * bfu_hi(r1);
        c0 += w2 * bfu_lo(r2); c1 += w2 * bfu_hi(r2);
        d0v += w3 * bfu_lo(r3); d1v += w3 * bfu_hi(r3);
    }
    for (; p < e0; ++p) {
        int2 q = csr[p];
        float w = __int_as_float(q.y);
        unsigned r = xb[(size_t)q.x * 64 + lane];
        a0 += w * bfu_lo(r); a1 += w * bfu_hi(r);
    }
    a0 = (a0 + b0) + (c0 + d0v);
    a1 = (a1 + b1) + (c1 + d1v);
    float di = dinv[node];
    float d2 = di * di;
    a0 += d2 * bfu_lo(rs);
    a1 += d2 * bfu_hi(rs);
    unsigned short h0 = f2bf(a0), h1 = f2bf(a1);
    xin_hi[(size_t)node * 64 + lane] = (unsigned)h0 | ((unsigned)h1 << 16);
    unsigned short l0 = f2bf(a0 - bf2f(h0)), l1 = f2bf(a1 - bf2f(h1));
    xin_lo[(size_t)node * 64 + lane] = (unsigned)l0 | ((unsigned)l1 << 16);
}

// ---------------- fused GEMM: h = relu(xin@W1+b1) -> LDS; h2b = h@W2 ----------------
// Block = 128 rows, 4 waves (wave = 32 rows). LDS h-tile 128x256 bf16 (64KB),
// 16B-block XOR swizzle so phase-2 ds_read_b128 is conflict-free.
__global__ __launch_bounds__(256) void gemm12_kernel(
    const unsigned short* __restrict__ Ahi, const unsigned short* __restrict__ Alo,
    const unsigned short* __restrict__ W1thi, const unsigned short* __restrict__ W1tlo,
    const float* __restrict__ b1,
    const unsigned short* __restrict__ W2thi, const unsigned short* __restrict__ W2tlo,
    unsigned short* __restrict__ h2b, int n) {
    __shared__ unsigned short hsh[32768];   // 128 rows x 256 cols bf16, swizzled
    int w = threadIdx.x >> 6, l = threadIdx.x & 63;
    int m0 = blockIdx.x * 128;
    int mrel = w * 32;
    int col16 = l & 15;
    int koff = (l >> 4) * 8;
    int rowA0 = m0 + mrel + col16;       if (rowA0 >= n) rowA0 = n - 1;
    int rowA1 = m0 + mrel + 16 + col16;  if (rowA1 >= n) rowA1 = n - 1;

    // ---- phase 1: h = relu(xin @ W1 + b1), 32 rows x 256 cols per wave ----
    f32x4 acc[2][4][4];   // [row-group][jt(64-col tile)][c(16-col)]
#pragma unroll
    for (int g = 0; g < 2; ++g)
#pragma unroll
        for (int jt = 0; jt < 4; ++jt)
#pragma unroll
            for (int c = 0; c < 4; ++c) acc[g][jt][c] = (f32x4){0.f, 0.f, 0.f, 0.f};
    for (int k0 = 0; k0 < 128; k0 += 32) {
        bf16x8 ah0 = *(const bf16x8*)&Ahi[(size_t)rowA0 * 128 + k0 + koff];
        bf16x8 al0 = *(const bf16x8*)&Alo[(size_t)rowA0 * 128 + k0 + koff];
        bf16x8 ah1 = *(const bf16x8*)&Ahi[(size_t)rowA1 * 128 + k0 + koff];
        bf16x8 al1 = *(const bf16x8*)&Alo[(size_t)rowA1 * 128 + k0 + koff];
#pragma unroll
        for (int jt = 0; jt < 4; ++jt) {
#pragma unroll
            for (int c = 0; c < 4; ++c) {
                size_t wb = (size_t)(jt * 64 + c * 16 + col16) * 128 + k0 + koff;
                bf16x8 wh = *(const bf16x8*)&W1thi[wb];
                bf16x8 wl = *(const bf16x8*)&W1tlo[wb];
                acc[0][jt][c] = __builtin_amdgcn_mfma_f32_16x16x32_bf16(ah0, wh, acc[0][jt][c], 0, 0, 0);
                acc[0][jt][c] = __builtin_amdgcn_mfma_f32_16x16x32_bf16(al0, wh, acc[0][jt][c], 0, 0, 0);
                acc[0][jt][c] = __builtin_amdgcn_mfma_f32_16x16x32_bf16(ah0, wl, acc[0][jt][c], 0, 0, 0);
                acc[1][jt][c] = __builtin_amdgcn_mfma_f32_16x16x32_bf16(ah1, wh, acc[1][jt][c], 0, 0, 0);
                acc[1][jt][c] = __builtin_amdgcn_mfma_f32_16x16x32_bf16(al1, wh, acc[1][jt][c], 0, 0, 0);
                acc[1][jt][c] = __builtin_amdgcn_mfma_f32_16x16x32_bf16(ah1, wl, acc[1][jt][c], 0, 0, 0);
            }
        }
    }
    // store h to LDS (bias+relu, bf16, swizzled): h[row][col] at row*256 + ((col>>3)^(row&7))*8 + (col&7)
#pragma unroll
    for (int g = 0; g < 2; ++g) {
#pragma unroll
        for (int jt = 0; jt < 4; ++jt) {
#pragma unroll
            for (int c = 0; c < 4; ++c) {
                int col = jt * 64 + c * 16 + col16;
#pragma unroll
                for (int r = 0; r < 4; ++r) {
                    int row = mrel + g * 16 + (l >> 4) * 4 + r;
                    float v = fmaxf(acc[g][jt][c][r] + b1[col], 0.f);
                    int idx = row * 256 + (((col >> 3) ^ (row & 7)) << 3) + (col & 7);
                    hsh[idx] = f2bf(v);
                }
            }
        }
    }
    __syncthreads();

    // ---- phase 2: h2b = h @ W2, 32 rows x 128 cols per wave, A from LDS ----
    int row20 = mrel + col16;        // block-relative
    int row21 = mrel + 16 + col16;
    f32x4 acc2[2][2][4];
#pragma unroll
    for (int g = 0; g < 2; ++g)
#pragma unroll
        for (int jt = 0; jt < 2; ++jt)
#pragma unroll
            for (int c = 0; c < 4; ++c) acc2[g][jt][c] = (f32x4){0.f, 0.f, 0.f, 0.f};
    for (int k0 = 0; k0 < 256; k0 += 32) {
        int cb = (k0 + koff) >> 3;
        bf16x8 ah0 = *(const bf16x8*)&hsh[row20 * 256 + ((cb ^ (row20 & 7)) << 3)];
        bf16x8 ah1 = *(const bf16x8*)&hsh[row21 * 256 + ((cb ^ (row21 & 7)) << 3)];
#pragma unroll
        for (int jt = 0; jt < 2; ++jt) {
#pragma unroll
            for (int c = 0; c < 4; ++c) {
                size_t wb = (size_t)(jt * 64 + c * 16 + col16) * 256 + k0 + koff;
                bf16x8 wh = *(const bf16x8*)&W2thi[wb];
                bf16x8 wl = *(const bf16x8*)&W2tlo[wb];
                acc2[0][jt][c] = __builtin_amdgcn_mfma_f32_16x16x32_bf16(ah0, wh, acc2[0][jt][c], 0, 0, 0);
                acc2[0][jt][c] = __builtin_amdgcn_mfma_f32_16x16x32_bf16(ah0, wl, acc2[0][jt][c], 0, 0, 0);
                acc2[1][jt][c] = __builtin_amdgcn_mfma_f32_16x16x32_bf16(ah1, wh, acc2[1][jt][c], 0, 0, 0);
                acc2[1][jt][c] = __builtin_amdgcn_mfma_f32_16x16x32_bf16(ah1, wl, acc2[1][jt][c], 0, 0, 0);
            }
        }
    }
#pragma unroll
    for (int g = 0; g < 2; ++g) {
#pragma unroll
        for (int jt = 0; jt < 2; ++jt) {
#pragma unroll
            for (int c = 0; c < 4; ++c) {
                int col = jt * 64 + c * 16 + col16;
#pragma unroll
                for (int r = 0; r < 4; ++r) {
                    int orow = m0 + mrel + g * 16 + (l >> 4) * 4 + r;
                    if (orow >= n) continue;
                    h2b[(size_t)orow * 128 + col] = f2bf(acc2[g][jt][c][r]);
                }
            }
        }
    }
}

// ---------------- conv2 gather (bf16, 8-way MLP) + epilogue + logits + edge partials + gsum — r6 form ----------------
__global__ __launch_bounds__(256) void conv2_fused_kernel(
    const unsigned int* __restrict__ h2b, const int2* __restrict__ csr,
    const int* __restrict__ local, const int* __restrict__ boff,
    const int* __restrict__ deg,
    const float* __restrict__ dinv, const float* __restrict__ b2,
    const float* __restrict__ npW, const float* __restrict__ npb,
    const float* __restrict__ epW, const float* __restrict__ epb,
    float* __restrict__ out_nl, float* __restrict__ uv,
    float* __restrict__ gsum, int n) {
    __shared__ float lgs[4][128];
    int lane = threadIdx.x & 63;
    int wid = threadIdx.x >> 6;
    int d0 = lane * 2, d1 = lane * 2 + 1;
    float wn00 = npW[d0 * 3 + 0], wn10 = npW[d0 * 3 + 1], wn20 = npW[d0 * 3 + 2];
    float wn01 = npW[d1 * 3 + 0], wn11 = npW[d1 * 3 + 1], wn21 = npW[d1 * 3 + 2];
    float wu00 = epW[d0 * 2 + 0], wu10 = epW[d0 * 2 + 1];
    float wu01 = epW[d1 * 2 + 0], wu11 = epW[d1 * 2 + 1];
    float wv00 = epW[(d0 + 128) * 2 + 0], wv10 = epW[(d0 + 128) * 2 + 1];
    float wv01 = epW[(d1 + 128) * 2 + 0], wv11 = epW[(d1 + 128) * 2 + 1];
    float b20 = b2[d0], b21 = b2[d1];
    float npb0 = npb[0], npb1 = npb[1], npb2 = npb[2];
    float epb0 = epb[0], epb1 = epb[1];
    float p0 = 0.f, p1 = 0.f;   // pool partials

    for (int node = blockIdx.x * 4 + wid; node < n; node += gridDim.x * 4) {
        int p = local[node] + boff[node >> 10];
        int e0 = p + deg[node];
        unsigned rs = h2b[(size_t)node * 64 + lane];
        float a0 = 0.f, a1 = 0.f, b0 = 0.f, b1 = 0.f;
        float c0 = 0.f, c1 = 0.f, e0v = 0.f, e1v = 0.f;
        for (; p + 7 < e0; p += 8) {
            int2 q0 = csr[p], q1 = csr[p + 1], q2 = csr[p + 2], q3 = csr[p + 3];
            int2 q4 = csr[p + 4], q5 = csr[p + 5], q6 = csr[p + 6], q7 = csr[p + 7];
            unsigned r0 = h2b[(size_t)q0.x * 64 + lane];
            unsigned r1 = h2b[(size_t)q1.x * 64 + lane];
            unsigned r2 = h2b[(size_t)q2.x * 64 + lane];
            unsigned r3 = h2b[(size_t)q3.x * 64 + lane];
            unsigned r4 = h2b[(size_t)q4.x * 64 + lane];
            unsigned r5 = h2b[(size_t)q5.x * 64 + lane];
            unsigned r6 = h2b[(size_t)q6.x * 64 + lane];
            unsigned r7 = h2b[(size_t)q7.x * 64 + lane];
            float w0 = __int_as_float(q0.y), w1 = __int_as_float(q1.y);
            float w2 = __int_as_float(q2.y), w3 = __int_as_float(q3.y);
            float w4 = __int_as_float(q4.y), w5 = __int_as_float(q5.y);
            float w6 = __int_as_float(q6.y), w7 = __int_as_float(q7.y);
            a0 += w0 * bfu_lo(r0); a1 += w0 * bfu_hi(r0);
            b0 += w1 * bfu_lo(r1); b1 += w1 * bfu_hi(r1);
            c0 += w2 * bfu_lo(r2); c1 += w2 * bfu_hi(r2);
            e0v += w3 * bfu_lo(r3); e1v += w3 * bfu_hi(r3);
            a0 += w4 * bfu_lo(r4); a1 += w4 * bfu_hi(r4);
            b0 += w5 * bfu_lo(r5); b1 += w5 * bfu_hi(r5);
            c0 += w6 * bfu_lo(r6); c1 += w6 * bfu_hi(r6);
            e0v += w7 * bfu_lo(r7); e1v += w7 * bfu_hi(r7);
        }
        for (; p + 3 < e0; p += 4) {
            int2 q0 = csr[p], q1 = csr[p + 1], q2 = csr[p + 2], q3 = csr[p + 3];
            unsigned r0 = h2b[(size_t)q0.x * 64 + lane];
            unsigned r1 = h2b[(size_t)q1.x * 64 + lane];
            unsigned r2 = h2b[(size_t)q2.x * 64 + lane];
            unsigned r3 = h2b[(size_t)q3.x * 64 + lane];
            float w0 = __int_as_float(q0.y), w1 = __int_as_float(q1.y);
            float w2 = __int_as_float(q2.y), w3 = __int_as_float(q3.y);
            a0 += w0 * bfu_lo(r0); a1 += w0 * bfu_hi(r0);
            b0 += w1 * bfu_lo(r1); b1 += w1 * bfu_hi(r1);
            c0 += w2 * bfu_lo(r2); c1 += w2 * bfu_hi(r2);
            e0v += w3 * bfu_lo(r3); e1v += w3 * bfu_hi(r3);
        }
        for (; p < e0; ++p) {
            int2 q = csr[p];
            float w = __int_as_float(q.y);
            unsigned r = h2b[(size_t)q.x * 64 + lane];
            a0 += w * bfu_lo(r); a1 += w * bfu_hi(r);
        }
        a0 = (a0 + b0) + (c0 + e0v);
        a1 = (a1 + b1) + (c1 + e1v);
        float di = dinv[node];
        float d2 = di * di;
        a0 = fmaxf(a0 + d2 * bfu_lo(rs) + b20, 0.f);
        a1 = fmaxf(a1 + d2 * bfu_hi(rs) + b21, 0.f);
        p0 += a0;
        p1 += a1;
        float n0 = a0 * wn00 + a1 * wn01;
        float n1 = a0 * wn10 + a1 * wn11;
        float n2 = a0 * wn20 + a1 * wn21;
        float u0 = a0 * wu00 + a1 * wu01;
        float u1 = a0 * wu10 + a1 * wu11;
        float v0 = a0 * wv00 + a1 * wv01;
        float v1 = a0 * wv10 + a1 * wv11;
        for (int off = 32; off; off >>= 1) {
            n0 += __shfl_xor(n0, off);
            n1 += __shfl_xor(n1, off);
            n2 += __shfl_xor(n2, off);
            u0 += __shfl_xor(u0, off);
            u1 += __shfl_xor(u1, off);
            v0 += __shfl_xor(v0, off);
            v1 += __shfl_xor(v1, off);
        }
        if (lane == 0) {
            out_nl[(size_t)node * 3 + 0] = n0 + npb0;
            out_nl[(size_t)node * 3 + 1] = n1 + npb1;
            out_nl[(size_t)node * 3 + 2] = n2 + npb2;
            float4 o;
            o.x = u0 + epb0; o.y = u1 + epb1; o.z = v0; o.w = v1;
            *(float4*)&uv[(size_t)node * 4] = o;
        }
    }
    lgs[wid][d0] = p0;
    lgs[wid][d1] = p1;
    __syncthreads();
    int t = threadIdx.x;
    if (t < 128) {
        float tot = lgs[0][t] + lgs[1][t] + lgs[2][t] + lgs[3][t];
        atomicAdd(&gsum[t], tot);
    }
}

// ---------------- edge logits (blocks 1..) + pooled heads (block 0) ----------------
__global__ __launch_bounds__(256) void edge_head_kernel(
    const float* __restrict__ uv, const int* __restrict__ src, const int* __restrict__ dst,
    float* __restrict__ out_el, int nE,
    const float* __restrict__ gsum,
    const float* __restrict__ fc1W, const float* __restrict__ fc1b,
    const float* __restrict__ fc2W, const float* __restrict__ fc2b,
    const float* __restrict__ gpW, const float* __restrict__ gpb,
    float* __restrict__ out_gl, float* __restrict__ out_val, int n) {
    if (blockIdx.x == 0) {
        __shared__ float g[128];
        __shared__ float red[256];
        int t = threadIdx.x;
        if (t < 128) g[t] = gsum[t] * (1.0f / (float)n);
        __syncthreads();
        float v = fc1b[t];
#pragma unroll
        for (int k = 0; k < 128; ++k) v += g[k] * fc1W[k * 256 + t];
        v = fmaxf(v, 0.0f);
        red[t] = v * fc2W[t];
        __syncthreads();
        for (int s = 128; s > 0; s >>= 1) { if (t < s) red[t] += red[t + s]; __syncthreads(); }
        if (t == 0) out_val[0] = red[0] + fc2b[0];
        __syncthreads();
        red[t] = (t < 128) ? g[t] * gpW[t] : 0.0f;
        __syncthreads();
        for (int s = 128; s > 0; s >>= 1) { if (t < s) red[t] += red[t + s]; __syncthreads(); }
        if (t == 0) out_gl[0] = red[0] + gpb[0];
        return;
    }
    int e = (blockIdx.x - 1) * blockDim.x + threadIdx.x;
    if (e >= nE) return;
    int s = src[e], d = dst[e];
    float2 u = *(const float2*)&uv[(size_t)s * 4];
    float2 v = *(const float2*)&uv[(size_t)d * 4 + 2];
    float2 o; o.x = u.x + v.x; o.y = u.y + v.y;
    *(float2*)&out_el[(size_t)e * 2] = o;
}

extern "C" void kernel_launch(void* const* d_in, const int* in_sizes, int n_in,
                              void* d_out, int out_size, void* d_ws, size_t ws_size,
                              hipStream_t stream) {
    const float* x    = (const float*)d_in[0];
    const int*   ei   = (const int*)d_in[1];
    const float* W1   = (const float*)d_in[2];
    const float* b1   = (const float*)d_in[3];
    const float* W2   = (const float*)d_in[4];
    const float* b2   = (const float*)d_in[5];
    const float* fc1W = (const float*)d_in[6];
    const float* fc1b = (const float*)d_in[7];
    const float* fc2W = (const float*)d_in[8];
    const float* fc2b = (const float*)d_in[9];
    const float* npW  = (const float*)d_in[10];
    const float* npb  = (const float*)d_in[11];
    const float* epW  = (const float*)d_in[12];
    const float* epb  = (const float*)d_in[13];
    const float* gpW  = (const float*)d_in[14];
    const float* gpb  = (const float*)d_in[15];
    float* out = (float*)d_out;

    const int n = in_sizes[0] / 128;   // 50000
    const int E = in_sizes[1] / 2;     // 800000
    const int* src = ei;
    const int* dst = ei + E;
    const int nb = (n + 1023) / 1024;  // scan blocks (<= 64)

    // workspace layout (256 B aligned chunks)
    char* p = (char*)d_ws;
    auto alloc = [&](size_t bytes) { char* r = p; p += (bytes + 255) & ~(size_t)255; return r; };
    unsigned short* xb     = (unsigned short*)alloc((size_t)n * 128 * 2);  // reused as h2b
    unsigned short* xin_hi = (unsigned short*)alloc((size_t)n * 128 * 2);
    unsigned short* xin_lo = (unsigned short*)alloc((size_t)n * 128 * 2);
    unsigned short* W1t_hi = (unsigned short*)alloc(128 * 256 * 2);
    unsigned short* W1t_lo = (unsigned short*)alloc(128 * 256 * 2);
    unsigned short* W2t_hi = (unsigned short*)alloc(256 * 128 * 2);
    unsigned short* W2t_lo = (unsigned short*)alloc(256 * 128 * 2);
    int2*  csr    = (int2*)alloc((size_t)E * 8);
    int*   deg    = (int*)alloc((size_t)n * 4 * 2);   // deg, cnt (zeroed in prep)
    int*   cnt    = deg + n;
    int*   local  = (int*)alloc((size_t)n * 4);
    int*   bsum   = (int*)alloc(64 * 4);
    int*   boff   = (int*)alloc(64 * 4);
    float* dinv   = (float*)alloc((size_t)n * 4);
    float* uv     = (float*)alloc((size_t)n * 16);
    float* gsum   = (float*)alloc(512);
    unsigned short* h2b = xb;   // alias: xb dead after gather1

    // output layout
    float* out_nl  = out;
    float* out_el  = out + (size_t)n * 3;
    float* out_gl  = out + (size_t)n * 3 + (size_t)E * 2;
    float* out_val = out_gl + 1;

    // prep: cast + wsplits + zero (deg/cnt + gsum)
    {
        long total = (long)n * 32 + 65536 + 2L * n + 128;
        int blocks = (int)((total + 255) / 256);
        prep_kernel<<<blocks, 256, 0, stream>>>(x, xb, W1, W1t_hi, W1t_lo,
                                                W2, W2t_hi, W2t_lo, deg, gsum, n);
    }

    hist_kernel<<<(E + 255) / 256, 256, 0, stream>>>(dst, deg, E);
    scanA_kernel<<<nb, 1024, 0, stream>>>(deg, local, dinv, bsum, n);
    scanB_kernel<<<1, 64, 0, stream>>>(bsum, boff, nb);
    fill_kernel<<<(E + 255) / 256, 256, 0, stream>>>(src, dst, local, boff, cnt, dinv, csr, E);

    gather1_kernel<<<(n + 3) / 4, 256, 0, stream>>>((const unsigned int*)xb, csr, local, boff,
                                                    deg, dinv, (unsigned int*)xin_hi,
                                                    (unsigned int*)xin_lo, n);

    gemm12_kernel<<<(n + 127) / 128, 256, 0, stream>>>(xin_hi, xin_lo, W1t_hi, W1t_lo, b1,
                                                       W2t_hi, W2t_lo, h2b, n);

    conv2_fused_kernel<<<2048, 256, 0, stream>>>((const unsigned int*)h2b, csr, local, boff,
                                                 deg, dinv, b2, npW, npb, epW, epb,
                                                 out_nl, uv, gsum, n);

    edge_head_kernel<<<1 + (E + 255) / 256, 256, 0, stream>>>(uv, src, dst, out_el, E,
                                                              gsum, fc1W, fc1b, fc2W, fc2b,
                                                              gpW, gpb, out_gl, out_val, n);
}